// Round 18
// baseline (172.499 us; speedup 1.0000x reference)
//
#include <hip/hip_runtime.h>
#include <math.h>

#define NQ 12
#define MULT 3.1415925343968237f

typedef _Float16 f16x8 __attribute__((ext_vector_type(8)));
typedef _Float16 f16x2 __attribute__((ext_vector_type(2)));
typedef float f32x4 __attribute__((ext_vector_type(4)));

// pack two f32 -> pk-rtz f16x2 as raw u32
static __device__ __forceinline__ unsigned int pkh(float a, float b) {
    auto h = __builtin_amdgcn_cvt_pkrtz(a, b);
    return __builtin_bit_cast(unsigned int, h);
}

// qubit q <-> state bit (11-q). CNOT ring, range r, sequential (updated controls).
__host__ __device__ constexpr int cnotf(int s, int r) {
    for (int q = 0; q < NQ; ++q) {
        int tq = q + r; if (tq >= NQ) tq -= NQ;
        s ^= ((s >> (11 - q)) & 1) << (11 - tq);
    }
    return s;
}

// GF(2)-bijective LDS word map (round-5 derivation, numerics HW-validated).
// Bits 5,6 carry u0,u3 only -> zero for all A/B-phase write bases.
__host__ __device__ constexpr int wordL(int I, int u, int n) {
    int I2 = (I >> 2) & 1, I3 = (I >> 3) & 1;
    int u0 = u & 1, u1 = (u >> 1) & 1, u2 = (u >> 2) & 1, u3 = (u >> 3) & 1;
    int n0 = n & 1, n1 = (n >> 1) & 1, n2 = (n >> 2) & 1, n3 = (n >> 3) & 1;
    return (I & 3) | ((I2 ^ u1 ^ n0) << 2) | ((I3 ^ u2 ^ n1) << 3) |
           ((I2 ^ u2 ^ n2) << 4) | (u0 << 5) | (u3 << 6) | (n0 << 7) |
           (n1 << 8) | (n2 << 9) | (n3 << 10) | (u1 << 11);
}

// Prep: 36 fused 16x16 complex unitaries as per-lane MFMA A-fragments
// (f16, 2 row-tiles each) + CNOT-perm basis deltas. VERBATIM from round 5.
__global__ void vqc_prep(const float* __restrict__ th, _Float16* __restrict__ frag,
                         int* __restrict__ ptabd) {
    int gid = blockIdx.x * 256 + threadIdx.x;
    int job = gid >> 6, lane = gid & 63;
    if (job < 72) {
        int pg = job >> 1, R = job & 1;
        int layer = pg / 18, rem = pg % 18, depth = rem / 3, ph = rem % 3;
        float g[4][2][2][2];
        for (int j = 0; j < 4; ++j) {
            int q = 4 * ph + j;
            const float* w = th + (((layer * 6 + depth) * 12 + q) * 3);
            float phi = w[0], tht = w[1], om = w[2];
            float st, ct, spo, cpo, smo, cmo;
            sincosf(0.5f * tht, &st, &ct);
            sincosf(0.5f * (phi + om), &spo, &cpo);
            sincosf(0.5f * (phi - om), &smo, &cmo);
            g[j][0][0][0] = ct * cpo;  g[j][0][0][1] = -ct * spo;
            g[j][0][1][0] = -st * cmo; g[j][0][1][1] = -st * smo;
            g[j][1][0][0] = st * cmo;  g[j][1][0][1] = -st * smo;
            g[j][1][1][0] = ct * cpo;  g[j][1][1][1] = ct * spo;
        }
        int m = 16 * R + (lane & 15);
        int u = m >> 1, v = m & 1;
        float Wr[4], Wi[4];
        for (int c = 0; c < 4; ++c) {
            int up = (lane >> 4) * 4 + c;
            float ar = 1.f, ai = 0.f;
            for (int j = 0; j < 4; ++j) {
                int ub = (u >> (3 - j)) & 1, vb = (up >> (3 - j)) & 1;
                float gr = g[j][ub][vb][0], gi = g[j][ub][vb][1];
                float nr = ar * gr - ai * gi, ni = ar * gi + ai * gr;
                ar = nr; ai = ni;
            }
            Wr[c] = ar; Wi[c] = ai;
        }
        _Float16* o = frag + ((size_t)job * 64 + lane) * 8;
        for (int i = 0; i < 8; ++i) {
            int c = i >> 1, vp = i & 1;
            float val = (v == vp) ? Wr[c] : (v == 0 ? -Wi[c] : Wi[c]);
            o[i] = (_Float16)val;
        }
    }
    if (blockIdx.x == 0 && threadIdx.x < 72) {
        int d = threadIdx.x / 12, bb = threadIdx.x % 12;
        int sp = cnotf(1 << bb, d + 1);
        ptabd[threadIdx.x] = wordL((sp >> 8) & 15, sp & 15, (sp >> 4) & 15);
    }
}

// One phase: 16 b128 reads + 32 MFMA + cvt, then write-all (in-place, same-wave
// program-order DS). PERM=true folds the CNOT ring into the write addresses.
template <bool PERM>
static __device__ __forceinline__ void do_phase(
        unsigned int* __restrict__ sl, int rbase0, const int* __restrict__ UC,
        int wbase0, const int* __restrict__ WCN,
        uint4 fa, uint4 fb2, int pbL, int p0, int p3, int p4, int p5, int p6, int p7) {
    f16x8 a0 = __builtin_bit_cast(f16x8, fa);
    f16x8 a1 = __builtin_bit_cast(f16x8, fb2);
    f32x4 zero = {0.f, 0.f, 0.f, 0.f};
    unsigned int ow[16][4];
#pragma unroll
    for (int c = 0; c < 16; ++c) {
        f16x8 bf = __builtin_bit_cast(f16x8, *(const uint4*)&sl[rbase0 ^ UC[c]]);
        f32x4 ac0 = __builtin_amdgcn_mfma_f32_16x16x32_f16(a0, bf, zero, 0, 0, 0);
        f32x4 ac1 = __builtin_amdgcn_mfma_f32_16x16x32_f16(a1, bf, zero, 0, 0, 0);
        ow[c][0] = pkh(ac0[0], ac0[1]);
        ow[c][1] = pkh(ac0[2], ac0[3]);
        ow[c][2] = pkh(ac1[0], ac1[1]);
        ow[c][3] = pkh(ac1[2], ac1[3]);
    }
    if (!PERM) {
#pragma unroll
        for (int c = 0; c < 16; ++c) {
            unsigned int* slb = sl + (wbase0 ^ WCN[c]);
            slb[0]  = ow[c][0];
            slb[32] = ow[c][1];
            slb[64] = ow[c][2];
            slb[96] = ow[c][3];
        }
    } else {
#pragma unroll
        for (int c = 0; c < 16; ++c) {
            int pcc = ((c & 1) ? p4 : 0) ^ ((c & 2) ? p5 : 0) ^
                      ((c & 4) ? p6 : 0) ^ ((c & 8) ? p7 : 0);
            int wb = pbL ^ pcc;
            sl[wb]           = ow[c][0];
            sl[wb ^ p0]      = ow[c][1];
            sl[wb ^ p3]      = ow[c][2];
            sl[wb ^ p3 ^ p0] = ow[c][3];
        }
    }
}

// WAVE-PRIVATE main: 1 wave = 1 block = 1 state, 16KB LDS, in-place phases,
// ZERO __syncthreads. Round-18 delta: 64-thread blocks (16KB/block) so HW can
// pack up to 10 blocks/CU (residency was stuck ~2.7 blocks at 128-thr/32KB).
__global__ __launch_bounds__(64, 4) void vqc_main(
        const float* __restrict__ x, const uint4* __restrict__ frag,
        const int* __restrict__ ptabd, float* __restrict__ out, int nst) {
    __shared__ __align__(16) unsigned int sbuf[4096];  // 16KB, one wave
    const int lane = threadIdx.x & 63;
    const int b = blockIdx.x;
    if (b >= nst) return;
    unsigned int* sl = sbuf;

    const int rbase0 = wordL(4 * (lane >> 4), 0, lane & 15);
    const int wbase0 = wordL(lane & 15, 2 * (lane >> 4), 0);  // bits 5,6 == 0
    constexpr int UC[16] = {
        wordL(0,0,0),  wordL(0,1,0),  wordL(0,2,0),  wordL(0,3,0),
        wordL(0,4,0),  wordL(0,5,0),  wordL(0,6,0),  wordL(0,7,0),
        wordL(0,8,0),  wordL(0,9,0),  wordL(0,10,0), wordL(0,11,0),
        wordL(0,12,0), wordL(0,13,0), wordL(0,14,0), wordL(0,15,0)};
    constexpr int WCN[16] = {
        wordL(0,0,0),  wordL(0,0,1),  wordL(0,0,2),  wordL(0,0,3),
        wordL(0,0,4),  wordL(0,0,5),  wordL(0,0,6),  wordL(0,0,7),
        wordL(0,0,8),  wordL(0,0,9),  wordL(0,0,10), wordL(0,0,11),
        wordL(0,0,12), wordL(0,0,13), wordL(0,0,14), wordL(0,0,15)};

    float myang = 0.f;
#pragma unroll 1
    for (int l = 0; l < 2; ++l) {
        if (l == 0) myang = (lane < NQ) ? x[b * NQ + lane] : 0.f;
        float sv, cv;
        sincosf(0.5f * myang, &sv, &cv);
        float cq[NQ], sq[NQ];
#pragma unroll
        for (int q = 0; q < NQ; ++q) { cq[q] = __shfl(cv, q, 64); sq[q] = __shfl(sv, q, 64); }

        // ---- init product state (f16, layout L_A) ----
        {
            float Pn = 1.f;
#pragma unroll
            for (int j = 0; j < 4; ++j) Pn *= ((lane >> j) & 1) ? sq[7 - j] : cq[7 - j];
            float Phi = (((lane >> 4) & 1) ? sq[1] : cq[1]) * (((lane >> 4) & 2) ? sq[0] : cq[0]);
            float pre = Pn * Phi;
            float Plo0 = cq[3] * cq[2], Plo1 = sq[3] * cq[2];
            float Plo2 = cq[3] * sq[2], Plo3 = sq[3] * sq[2];
#pragma unroll
            for (int c = 0; c < 16; ++c) {
                float Pu = ((c & 1) ? sq[11] : cq[11]) * ((c & 2) ? sq[10] : cq[10]) *
                           ((c & 4) ? sq[9] : cq[9]) * ((c & 8) ? sq[8] : cq[8]);
                float base = pre * Pu;
                uint4 w;
                w.x = pkh(base * Plo0, 0.f);
                w.y = pkh(base * Plo1, 0.f);
                w.z = pkh(base * Plo2, 0.f);
                w.w = pkh(base * Plo3, 0.f);
                *(uint4*)&sl[rbase0 ^ UC[c]] = w;
            }
        }

#pragma unroll 1
        for (int d = 0; d < 6; ++d) {
            // prefetch: ALL 6 fragment b128 loads of this depth in flight
            const uint4* fbp = frag + (size_t)(l * 6 + d) * 384;
            uint4 af0 = fbp[lane];
            uint4 af1 = fbp[64 + lane];
            uint4 af2 = fbp[128 + lane];
            uint4 af3 = fbp[192 + lane];
            uint4 af4 = fbp[256 + lane];
            uint4 af5 = fbp[320 + lane];

            const int* pdp = ptabd + d * 12;
            int p0 = pdp[0], p1 = pdp[1], p2 = pdp[2], p3 = pdp[3];
            int p4 = pdp[4], p5 = pdp[5], p6 = pdp[6], p7 = pdp[7];
            int p8 = pdp[8], p9 = pdp[9], p10 = pdp[10], p11 = pdp[11];
            int pbL = 0;
            if (lane & 1)  pbL ^= p8;
            if (lane & 2)  pbL ^= p9;
            if (lane & 4)  pbL ^= p10;
            if (lane & 8)  pbL ^= p11;
            if (lane & 16) pbL ^= p1;
            if (lane & 32) pbL ^= p2;

            do_phase<false>(sl, rbase0, UC, wbase0, WCN, af0, af1, 0, 0, 0, 0, 0, 0, 0);
            do_phase<false>(sl, rbase0, UC, wbase0, WCN, af2, af3, 0, 0, 0, 0, 0, 0, 0);
            do_phase<true>(sl, rbase0, UC, wbase0, WCN, af4, af5, pbL, p0, p3, p4, p5, p6, p7);
        }

        // ---- readout (layout L_A), wave-local ----
        {
            float P = 0.f, e2 = 0.f, e3 = 0.f;
            float t8 = 0.f, t9 = 0.f, t10 = 0.f, t11 = 0.f;
#pragma unroll
            for (int c = 0; c < 16; ++c) {
                uint4 v = *(const uint4*)&sl[rbase0 ^ UC[c]];
                unsigned int arr[4] = {v.x, v.y, v.z, v.w};
                float tl = 0.f;
#pragma unroll
                for (int i = 0; i < 4; ++i) {
                    f16x2 h = __builtin_bit_cast(f16x2, arr[i]);
                    float re = (float)h[0], im = (float)h[1];
                    float p = re * re + im * im;
                    tl += p;
                    e2 += (i & 2) ? -p : p;
                    e3 += (i & 1) ? -p : p;
                }
                P += tl;
                t8  += (c & 8) ? -tl : tl;
                t9  += (c & 4) ? -tl : tl;
                t10 += (c & 2) ? -tl : tl;
                t11 += (c & 1) ? -tl : tl;
            }
            float r[12];
            r[0] = (lane & 32) ? -P : P;
            r[1] = (lane & 16) ? -P : P;
            r[2] = e2; r[3] = e3;
            r[4] = (lane & 8) ? -P : P;
            r[5] = (lane & 4) ? -P : P;
            r[6] = (lane & 2) ? -P : P;
            r[7] = (lane & 1) ? -P : P;
            r[8] = t8; r[9] = t9; r[10] = t10; r[11] = t11;
#pragma unroll
            for (int k = 0; k < 12; ++k) {
#pragma unroll
                for (int m = 1; m < 64; m <<= 1) r[k] += __shfl_xor(r[k], m, 64);
            }
            if (l == 0) {
                myang = (lane == 0) ? r[0] : (lane == 1) ? r[1] : (lane == 2) ? r[2] :
                        (lane == 3) ? r[3] : (lane == 4) ? r[4] : (lane == 5) ? r[5] :
                        (lane == 6) ? r[6] : (lane == 7) ? r[7] : (lane == 8) ? r[8] :
                        (lane == 9) ? r[9] : (lane == 10) ? r[10] : (lane == 11) ? r[11] : 0.f;
            } else {
                if (lane >= 3 && lane < 9) {
                    float v = (lane == 3) ? r[3] : (lane == 4) ? r[4] : (lane == 5) ? r[5] :
                              (lane == 6) ? r[6] : (lane == 7) ? r[7] : r[8];
                    out[b * 6 + (lane - 3)] = v * MULT;
                }
            }
        }
    }
}

extern "C" void kernel_launch(void* const* d_in, const int* in_sizes, int n_in,
                              void* d_out, int out_size, void* d_ws, size_t ws_size,
                              hipStream_t stream) {
    const float* x = (const float*)d_in[0];
    const float* th = (const float*)d_in[1];
    float* outp = (float*)d_out;
    _Float16* fragh = (_Float16*)d_ws;                    // 73728 B
    int* ptabd = (int*)((char*)d_ws + 73728);             // 288 B

    int batch = in_sizes[0] / NQ;

    hipLaunchKernelGGL(vqc_prep, dim3(18), dim3(256), 0, stream, th, fragh, ptabd);
    hipLaunchKernelGGL(vqc_main, dim3(batch), dim3(64), 0, stream, x,
                       (const uint4*)fragh, ptabd, outp, batch);
}

// Round 19
// 150.109 us; speedup vs baseline: 1.1492x; 1.1492x over previous
//
#include <hip/hip_runtime.h>
#include <math.h>

#define NQ 12
#define MULT 3.1415925343968237f

typedef _Float16 f16x8 __attribute__((ext_vector_type(8)));
typedef _Float16 f16x2 __attribute__((ext_vector_type(2)));
typedef float f32x4 __attribute__((ext_vector_type(4)));

// pack two f32 -> pk-rtz f16x2 as raw u32
static __device__ __forceinline__ unsigned int pkh(float a, float b) {
    auto h = __builtin_amdgcn_cvt_pkrtz(a, b);
    return __builtin_bit_cast(unsigned int, h);
}

// qubit q <-> state bit (11-q). CNOT ring, range r, sequential (updated controls).
__host__ __device__ constexpr int cnotf(int s, int r) {
    for (int q = 0; q < NQ; ++q) {
        int tq = q + r; if (tq >= NQ) tq -= NQ;
        s ^= ((s >> (11 - q)) & 1) << (11 - tq);
    }
    return s;
}

// GF(2)-bijective LDS word map (round-5 derivation, numerics HW-validated).
// Bits 5,6 carry u0,u3 only -> zero for all A/B-phase write bases.
__host__ __device__ constexpr int wordL(int I, int u, int n) {
    int I2 = (I >> 2) & 1, I3 = (I >> 3) & 1;
    int u0 = u & 1, u1 = (u >> 1) & 1, u2 = (u >> 2) & 1, u3 = (u >> 3) & 1;
    int n0 = n & 1, n1 = (n >> 1) & 1, n2 = (n >> 2) & 1, n3 = (n >> 3) & 1;
    return (I & 3) | ((I2 ^ u1 ^ n0) << 2) | ((I3 ^ u2 ^ n1) << 3) |
           ((I2 ^ u2 ^ n2) << 4) | (u0 << 5) | (u3 << 6) | (n0 << 7) |
           (n1 << 8) | (n2 << 9) | (n3 << 10) | (u1 << 11);
}

// Prep: 36 fused 16x16 complex unitaries as per-lane MFMA A-fragments
// (f16, 2 row-tiles each) + CNOT-perm basis deltas. VERBATIM from round 5.
__global__ void vqc_prep(const float* __restrict__ th, _Float16* __restrict__ frag,
                         int* __restrict__ ptabd) {
    int gid = blockIdx.x * 256 + threadIdx.x;
    int job = gid >> 6, lane = gid & 63;
    if (job < 72) {
        int pg = job >> 1, R = job & 1;
        int layer = pg / 18, rem = pg % 18, depth = rem / 3, ph = rem % 3;
        float g[4][2][2][2];
        for (int j = 0; j < 4; ++j) {
            int q = 4 * ph + j;
            const float* w = th + (((layer * 6 + depth) * 12 + q) * 3);
            float phi = w[0], tht = w[1], om = w[2];
            float st, ct, spo, cpo, smo, cmo;
            sincosf(0.5f * tht, &st, &ct);
            sincosf(0.5f * (phi + om), &spo, &cpo);
            sincosf(0.5f * (phi - om), &smo, &cmo);
            g[j][0][0][0] = ct * cpo;  g[j][0][0][1] = -ct * spo;
            g[j][0][1][0] = -st * cmo; g[j][0][1][1] = -st * smo;
            g[j][1][0][0] = st * cmo;  g[j][1][0][1] = -st * smo;
            g[j][1][1][0] = ct * cpo;  g[j][1][1][1] = ct * spo;
        }
        int m = 16 * R + (lane & 15);
        int u = m >> 1, v = m & 1;
        float Wr[4], Wi[4];
        for (int c = 0; c < 4; ++c) {
            int up = (lane >> 4) * 4 + c;
            float ar = 1.f, ai = 0.f;
            for (int j = 0; j < 4; ++j) {
                int ub = (u >> (3 - j)) & 1, vb = (up >> (3 - j)) & 1;
                float gr = g[j][ub][vb][0], gi = g[j][ub][vb][1];
                float nr = ar * gr - ai * gi, ni = ar * gi + ai * gr;
                ar = nr; ai = ni;
            }
            Wr[c] = ar; Wi[c] = ai;
        }
        _Float16* o = frag + ((size_t)job * 64 + lane) * 8;
        for (int i = 0; i < 8; ++i) {
            int c = i >> 1, vp = i & 1;
            float val = (v == vp) ? Wr[c] : (v == 0 ? -Wi[c] : Wi[c]);
            o[i] = (_Float16)val;
        }
    }
    if (blockIdx.x == 0 && threadIdx.x < 72) {
        int d = threadIdx.x / 12, bb = threadIdx.x % 12;
        int sp = cnotf(1 << bb, d + 1);
        ptabd[threadIdx.x] = wordL((sp >> 8) & 15, sp & 15, (sp >> 4) & 15);
    }
}

// One phase: 16 b128 reads + 32 MFMA + cvt, then write-all (in-place, same-wave
// program-order DS). PERM=true folds the CNOT ring into the write addresses.
template <bool PERM>
static __device__ __forceinline__ void do_phase(
        unsigned int* __restrict__ sl, int rbase0, const int* __restrict__ UC,
        int wbase0, const int* __restrict__ WCN,
        uint4 fa, uint4 fb2, int pbL, int p0, int p3, int p4, int p5, int p6, int p7) {
    f16x8 a0 = __builtin_bit_cast(f16x8, fa);
    f16x8 a1 = __builtin_bit_cast(f16x8, fb2);
    f32x4 zero = {0.f, 0.f, 0.f, 0.f};
    unsigned int ow[16][4];
#pragma unroll
    for (int c = 0; c < 16; ++c) {
        f16x8 bf = __builtin_bit_cast(f16x8, *(const uint4*)&sl[rbase0 ^ UC[c]]);
        f32x4 ac0 = __builtin_amdgcn_mfma_f32_16x16x32_f16(a0, bf, zero, 0, 0, 0);
        f32x4 ac1 = __builtin_amdgcn_mfma_f32_16x16x32_f16(a1, bf, zero, 0, 0, 0);
        ow[c][0] = pkh(ac0[0], ac0[1]);
        ow[c][1] = pkh(ac0[2], ac0[3]);
        ow[c][2] = pkh(ac1[0], ac1[1]);
        ow[c][3] = pkh(ac1[2], ac1[3]);
    }
    if (!PERM) {
#pragma unroll
        for (int c = 0; c < 16; ++c) {
            unsigned int* slb = sl + (wbase0 ^ WCN[c]);
            slb[0]  = ow[c][0];
            slb[32] = ow[c][1];
            slb[64] = ow[c][2];
            slb[96] = ow[c][3];
        }
    } else {
#pragma unroll
        for (int c = 0; c < 16; ++c) {
            int pcc = ((c & 1) ? p4 : 0) ^ ((c & 2) ? p5 : 0) ^
                      ((c & 4) ? p6 : 0) ^ ((c & 8) ? p7 : 0);
            int wb = pbL ^ pcc;
            sl[wb]           = ow[c][0];
            sl[wb ^ p0]      = ow[c][1];
            sl[wb ^ p3]      = ow[c][2];
            sl[wb ^ p3 ^ p0] = ow[c][3];
        }
    }
}

// WAVE-PRIVATE main (r17 anchor): 1 wave = 1 state, 16KB private LDS slice,
// in-place phases, ZERO __syncthreads, depth-level fragment prefetch,
// 128-thr blocks. Best deterministic configuration (150.4 us).
__global__ __launch_bounds__(128, 2) void vqc_main(
        const float* __restrict__ x, const uint4* __restrict__ frag,
        const int* __restrict__ ptabd, float* __restrict__ out, int nst) {
    __shared__ __align__(16) unsigned int sbuf[8192];  // 2 waves x 16KB
    const int t = threadIdx.x, lane = t & 63, wv = t >> 6;
    const int b = blockIdx.x * 2 + wv;
    if (b >= nst) return;
    unsigned int* sl = sbuf + (wv << 12);

    const int rbase0 = wordL(4 * (lane >> 4), 0, lane & 15);
    const int wbase0 = wordL(lane & 15, 2 * (lane >> 4), 0);  // bits 5,6 == 0
    constexpr int UC[16] = {
        wordL(0,0,0),  wordL(0,1,0),  wordL(0,2,0),  wordL(0,3,0),
        wordL(0,4,0),  wordL(0,5,0),  wordL(0,6,0),  wordL(0,7,0),
        wordL(0,8,0),  wordL(0,9,0),  wordL(0,10,0), wordL(0,11,0),
        wordL(0,12,0), wordL(0,13,0), wordL(0,14,0), wordL(0,15,0)};
    constexpr int WCN[16] = {
        wordL(0,0,0),  wordL(0,0,1),  wordL(0,0,2),  wordL(0,0,3),
        wordL(0,0,4),  wordL(0,0,5),  wordL(0,0,6),  wordL(0,0,7),
        wordL(0,0,8),  wordL(0,0,9),  wordL(0,0,10), wordL(0,0,11),
        wordL(0,0,12), wordL(0,0,13), wordL(0,0,14), wordL(0,0,15)};

    float myang = 0.f;
#pragma unroll 1
    for (int l = 0; l < 2; ++l) {
        if (l == 0) myang = (lane < NQ) ? x[b * NQ + lane] : 0.f;
        float sv, cv;
        sincosf(0.5f * myang, &sv, &cv);
        float cq[NQ], sq[NQ];
#pragma unroll
        for (int q = 0; q < NQ; ++q) { cq[q] = __shfl(cv, q, 64); sq[q] = __shfl(sv, q, 64); }

        // ---- init product state (f16, layout L_A, private slice) ----
        {
            float Pn = 1.f;
#pragma unroll
            for (int j = 0; j < 4; ++j) Pn *= ((lane >> j) & 1) ? sq[7 - j] : cq[7 - j];
            float Phi = (((lane >> 4) & 1) ? sq[1] : cq[1]) * (((lane >> 4) & 2) ? sq[0] : cq[0]);
            float pre = Pn * Phi;
            float Plo0 = cq[3] * cq[2], Plo1 = sq[3] * cq[2];
            float Plo2 = cq[3] * sq[2], Plo3 = sq[3] * sq[2];
#pragma unroll
            for (int c = 0; c < 16; ++c) {
                float Pu = ((c & 1) ? sq[11] : cq[11]) * ((c & 2) ? sq[10] : cq[10]) *
                           ((c & 4) ? sq[9] : cq[9]) * ((c & 8) ? sq[8] : cq[8]);
                float base = pre * Pu;
                uint4 w;
                w.x = pkh(base * Plo0, 0.f);
                w.y = pkh(base * Plo1, 0.f);
                w.z = pkh(base * Plo2, 0.f);
                w.w = pkh(base * Plo3, 0.f);
                *(uint4*)&sl[rbase0 ^ UC[c]] = w;
            }
        }

#pragma unroll 1
        for (int d = 0; d < 6; ++d) {
            // prefetch: ALL 6 fragment b128 loads of this depth in flight
            const uint4* fbp = frag + (size_t)(l * 6 + d) * 384;
            uint4 af0 = fbp[lane];
            uint4 af1 = fbp[64 + lane];
            uint4 af2 = fbp[128 + lane];
            uint4 af3 = fbp[192 + lane];
            uint4 af4 = fbp[256 + lane];
            uint4 af5 = fbp[320 + lane];

            const int* pdp = ptabd + d * 12;
            int p0 = pdp[0], p1 = pdp[1], p2 = pdp[2], p3 = pdp[3];
            int p4 = pdp[4], p5 = pdp[5], p6 = pdp[6], p7 = pdp[7];
            int p8 = pdp[8], p9 = pdp[9], p10 = pdp[10], p11 = pdp[11];
            int pbL = 0;
            if (lane & 1)  pbL ^= p8;
            if (lane & 2)  pbL ^= p9;
            if (lane & 4)  pbL ^= p10;
            if (lane & 8)  pbL ^= p11;
            if (lane & 16) pbL ^= p1;
            if (lane & 32) pbL ^= p2;

            do_phase<false>(sl, rbase0, UC, wbase0, WCN, af0, af1, 0, 0, 0, 0, 0, 0, 0);
            do_phase<false>(sl, rbase0, UC, wbase0, WCN, af2, af3, 0, 0, 0, 0, 0, 0, 0);
            do_phase<true>(sl, rbase0, UC, wbase0, WCN, af4, af5, pbL, p0, p3, p4, p5, p6, p7);
        }

        // ---- readout (layout L_A), wave-local ----
        {
            float P = 0.f, e2 = 0.f, e3 = 0.f;
            float t8 = 0.f, t9 = 0.f, t10 = 0.f, t11 = 0.f;
#pragma unroll
            for (int c = 0; c < 16; ++c) {
                uint4 v = *(const uint4*)&sl[rbase0 ^ UC[c]];
                unsigned int arr[4] = {v.x, v.y, v.z, v.w};
                float tl = 0.f;
#pragma unroll
                for (int i = 0; i < 4; ++i) {
                    f16x2 h = __builtin_bit_cast(f16x2, arr[i]);
                    float re = (float)h[0], im = (float)h[1];
                    float p = re * re + im * im;
                    tl += p;
                    e2 += (i & 2) ? -p : p;
                    e3 += (i & 1) ? -p : p;
                }
                P += tl;
                t8  += (c & 8) ? -tl : tl;
                t9  += (c & 4) ? -tl : tl;
                t10 += (c & 2) ? -tl : tl;
                t11 += (c & 1) ? -tl : tl;
            }
            float r[12];
            r[0] = (lane & 32) ? -P : P;
            r[1] = (lane & 16) ? -P : P;
            r[2] = e2; r[3] = e3;
            r[4] = (lane & 8) ? -P : P;
            r[5] = (lane & 4) ? -P : P;
            r[6] = (lane & 2) ? -P : P;
            r[7] = (lane & 1) ? -P : P;
            r[8] = t8; r[9] = t9; r[10] = t10; r[11] = t11;
#pragma unroll
            for (int k = 0; k < 12; ++k) {
#pragma unroll
                for (int m = 1; m < 64; m <<= 1) r[k] += __shfl_xor(r[k], m, 64);
            }
            if (l == 0) {
                myang = (lane == 0) ? r[0] : (lane == 1) ? r[1] : (lane == 2) ? r[2] :
                        (lane == 3) ? r[3] : (lane == 4) ? r[4] : (lane == 5) ? r[5] :
                        (lane == 6) ? r[6] : (lane == 7) ? r[7] : (lane == 8) ? r[8] :
                        (lane == 9) ? r[9] : (lane == 10) ? r[10] : (lane == 11) ? r[11] : 0.f;
            } else {
                if (lane >= 3 && lane < 9) {
                    float v = (lane == 3) ? r[3] : (lane == 4) ? r[4] : (lane == 5) ? r[5] :
                              (lane == 6) ? r[6] : (lane == 7) ? r[7] : r[8];
                    out[b * 6 + (lane - 3)] = v * MULT;
                }
            }
        }
    }
}

extern "C" void kernel_launch(void* const* d_in, const int* in_sizes, int n_in,
                              void* d_out, int out_size, void* d_ws, size_t ws_size,
                              hipStream_t stream) {
    const float* x = (const float*)d_in[0];
    const float* th = (const float*)d_in[1];
    float* outp = (float*)d_out;
    _Float16* fragh = (_Float16*)d_ws;                    // 73728 B
    int* ptabd = (int*)((char*)d_ws + 73728);             // 288 B

    int batch = in_sizes[0] / NQ;
    int blocks = (batch + 1) / 2;

    hipLaunchKernelGGL(vqc_prep, dim3(18), dim3(256), 0, stream, th, fragh, ptabd);
    hipLaunchKernelGGL(vqc_main, dim3(blocks), dim3(128), 0, stream, x,
                       (const uint4*)fragh, ptabd, outp, batch);
}